// Round 3
// baseline (177.606 us; speedup 1.0000x reference)
//
#include <hip/hip_runtime.h>

typedef __bf16 bf16x8 __attribute__((ext_vector_type(8)));
typedef float f32x4 __attribute__((ext_vector_type(4)));
typedef float f32x16 __attribute__((ext_vector_type(16)));
typedef unsigned short u16x8 __attribute__((ext_vector_type(8)));

#define DEVI static __device__ __forceinline__

DEVI unsigned short f2b(float x) {
  __bf16 b = (__bf16)x;           // native v_cvt on gfx950, RNE
  return __builtin_bit_cast(unsigned short, b);
}

// Pre-pack W2 into per-lane MFMA B-fragment order, bf16.
// p1 (GEMM1, 32x32x16): frag[s 0..31][t0 0..15]: lane l, elem j holds
//   W2[k = s*16 + (l>>5)*8 + j][c = t0*32 + (l&31)]
// p2 (GEMM2, 16x16x32): frag[s 0..15][t0 0..31]: lane l, elem j holds
//   W2^T[c = s*32 + (l>>4)*8 + j][h = t0*16 + (l&15)] = W2[h][c]
__global__ __launch_bounds__(256) void pack_w2_kernel(
    const float* __restrict__ W2, unsigned short* __restrict__ p1,
    unsigned short* __restrict__ p2) {
  int idx = blockIdx.x * 256 + threadIdx.x;   // 0 .. 524287
  int which = idx >> 18;
  int i = idx & 262143;
  int j = i & 7;
  int l = (i >> 3) & 63;
  if (which == 0) {
    int t0 = (i >> 9) & 15;
    int s = i >> 13;            // 0..31
    p1[i] = f2b(W2[(s * 16 + (l >> 5) * 8 + j) * 512 + t0 * 32 + (l & 31)]);
  } else {
    int t0 = (i >> 9) & 31;
    int s = i >> 14;            // 0..15
    p2[i] = f2b(W2[(t0 * 16 + (l & 15)) * 512 + s * 32 + (l >> 4) * 8 + j]);
  }
}

__global__ __launch_bounds__(256, 2) void phm_kernel(
    const float* __restrict__ state, const float* __restrict__ action_emb,
    const float* __restrict__ W1, const float* __restrict__ b1,
    const float* __restrict__ b2, const float* __restrict__ W3,
    const float* __restrict__ log_damping, const float* __restrict__ Gw,
    const float* __restrict__ Gb, const unsigned short* __restrict__ packB1,
    const unsigned short* __restrict__ packB2, float* __restrict__ out) {
  // buf (64KB) is reused: GEMM1 A-fragments (h1) -> GEMM2 A-fragments (dz2).
  // Both layouts are fragment-linear: page*1024 + slot*16 + j*2.
  __shared__ unsigned short buf[64 * 512];
  __shared__ float W1s[1024];
  __shared__ float b1s[512];
  __shared__ float b2s[512];
  __shared__ float W3s[512];
  __shared__ float st[128];
  __shared__ float part[4][64][2];

  const int t = threadIdx.x;
  const int lane = t & 63;
  const int wid = t >> 6;
  const int l15 = lane & 15;
  const int l4 = lane >> 4;
  const int l31 = lane & 31;
  const int l5 = lane >> 5;
  const long row0 = (long)blockIdx.x * 64;
  char* bufc = reinterpret_cast<char*>(buf);

  // ---- stage small tables ----
  for (int i = t; i < 512; i += 256) {
    W1s[i] = W1[i];
    W1s[512 + i] = W1[512 + i];
    b1s[i] = b1[i];
    b2s[i] = b2[i];
    W3s[i] = W3[i];
  }
  if (t < 128) st[t] = state[row0 * 2 + t];
  __syncthreads();

  // ---- phase 0: h1 = softplus(state @ W1 + b1) -> GEMM1-A fragments ----
  // slot(page = s*2+rt, lane): h1[row = rt*32 + (lane&31)][k = s*16 + (lane>>5)*8 + j]
  for (int it = 0; it < 16; ++it) {
    int page = it * 4 + wid;
    int s = page >> 1, rt = page & 1;
    int row = rt * 32 + l31;
    int k0 = s * 16 + l5 * 8;
    float s0 = st[row * 2], s1 = st[row * 2 + 1];
    u16x8 pk;
#pragma unroll
    for (int j = 0; j < 8; ++j) {
      int c = k0 + j;
      float z = fmaf(s0, W1s[c], fmaf(s1, W1s[512 + c], b1s[c]));
      float e = __expf(-fabsf(z));
      float h = fmaxf(z, 0.f) + __logf(1.f + e);
      pk[j] = f2b(h);
    }
    *reinterpret_cast<u16x8*>(bufc + page * 1024 + lane * 16) = pk;
  }
  __syncthreads();

  // ---- GEMM1: z2 = h1 @ W2, 32x32x16 MFMA, waves split 128 cols each ----
  f32x16 acc1[2][4];
#pragma unroll
  for (int rt = 0; rt < 2; ++rt)
#pragma unroll
    for (int ct = 0; ct < 4; ++ct)
#pragma unroll
      for (int r = 0; r < 16; ++r) acc1[rt][ct][r] = 0.f;

#pragma unroll 4
  for (int s = 0; s < 32; ++s) {
    bf16x8 af[2];
#pragma unroll
    for (int rt = 0; rt < 2; ++rt)
      af[rt] = __builtin_bit_cast(
          bf16x8, *reinterpret_cast<const int4*>(
                      bufc + (s * 2 + rt) * 1024 + lane * 16));
    bf16x8 bfr[4];
#pragma unroll
    for (int ct = 0; ct < 4; ++ct)
      bfr[ct] = __builtin_bit_cast(
          bf16x8, *reinterpret_cast<const int4*>(
                      packB1 + ((s * 16 + wid * 4 + ct) * 64 + lane) * 8));
#pragma unroll
    for (int rt = 0; rt < 2; ++rt)
#pragma unroll
      for (int ct = 0; ct < 4; ++ct)
        acc1[rt][ct] = __builtin_amdgcn_mfma_f32_32x32x16_bf16(
            af[rt], bfr[ct], acc1[rt][ct], 0, 0, 0);
  }
  __syncthreads();   // all waves done reading h1 fragments

  // ---- epi1: dz2 = W3 * sigmoid(z2 + b2) -> GEMM2-A fragments ----
  // 32x32 C/D: col = l&31, row = rt*32 + (reg&3) + 8*(reg>>2) + 4*(l>>5)
  // Target slot for dz2[row][c]: page = (c>>5)*4 + (row>>4),
  //   lane2 = (row&15) + 16*((c>>3)&3), slot = lane2 ^ (lane2>>4), byte j = c&7.
#pragma unroll
  for (int rt = 0; rt < 2; ++rt) {
#pragma unroll
    for (int ct = 0; ct < 4; ++ct) {
      int c = wid * 128 + ct * 32 + l31;
      float w3 = W3s[c], bb = b2s[c];
      int pbase = (c >> 5) * 4096 + (c & 7) * 2;
      int oct = (l31 >> 3);
#pragma unroll
      for (int reg = 0; reg < 16; ++reg) {
        int row = rt * 32 + (reg & 3) + 8 * (reg >> 2) + 4 * l5;
        float z2 = acc1[rt][ct][reg] + bb;
        float sg = __builtin_amdgcn_rcpf(1.f + __expf(-z2));
        unsigned short u = f2b(w3 * sg);
        int lane2 = (row & 15) + 16 * oct;
        int slot = lane2 ^ (lane2 >> 4);
        *reinterpret_cast<unsigned short*>(
            bufc + pbase + (row >> 4) * 1024 + slot * 16) = u;
      }
    }
  }
  __syncthreads();

  // hoist this lane's (s0,s1) pairs for the 16 C/D rows it owns in GEMM2
  float2 sv[16];
#pragma unroll
  for (int rt2 = 0; rt2 < 4; ++rt2)
#pragma unroll
    for (int jj = 0; jj < 4; ++jj) {
      int r = rt2 * 16 + l4 * 4 + jj;
      sv[rt2 * 4 + jj] = *reinterpret_cast<const float2*>(&st[r * 2]);
    }

  // ---- GEMM2: dh1 = dz2 @ W2^T, 16x16x32 MFMA ----
  f32x4 acc2[4][8];
#pragma unroll
  for (int a = 0; a < 4; ++a)
#pragma unroll
    for (int b = 0; b < 8; ++b)
#pragma unroll
      for (int r = 0; r < 4; ++r) acc2[a][b][r] = 0.f;

  const int rslot = (lane ^ (lane >> 4)) * 16;
#pragma unroll 2
  for (int s2 = 0; s2 < 16; ++s2) {
    bf16x8 af[4];
#pragma unroll
    for (int rt2 = 0; rt2 < 4; ++rt2)
      af[rt2] = __builtin_bit_cast(
          bf16x8, *reinterpret_cast<const int4*>(
                      bufc + s2 * 4096 + rt2 * 1024 + rslot));
    bf16x8 bfr[8];
#pragma unroll
    for (int ct2 = 0; ct2 < 8; ++ct2)
      bfr[ct2] = __builtin_bit_cast(
          bf16x8, *reinterpret_cast<const int4*>(
                      packB2 + ((s2 * 32 + wid * 8 + ct2) * 64 + lane) * 8));
#pragma unroll
    for (int rt2 = 0; rt2 < 4; ++rt2)
#pragma unroll
      for (int ct2 = 0; ct2 < 8; ++ct2)
        acc2[rt2][ct2] = __builtin_amdgcn_mfma_f32_16x16x32_bf16(
            af[rt2], bfr[ct2], acc2[rt2][ct2], 0, 0, 0);
  }

  // ---- epi2: dz1 = dh1 * sigmoid(z1); partial ds = dz1 @ W1^T ----
  float p0[16], p1v[16];
#pragma unroll
  for (int i = 0; i < 16; ++i) { p0[i] = 0.f; p1v[i] = 0.f; }

#pragma unroll
  for (int ct2 = 0; ct2 < 8; ++ct2) {
    int hc = wid * 128 + ct2 * 16 + l15;
    float w10 = W1s[hc], w11 = W1s[512 + hc], bb = b1s[hc];
#pragma unroll
    for (int rt2 = 0; rt2 < 4; ++rt2) {
#pragma unroll
      for (int jj = 0; jj < 4; ++jj) {
        float2 sp = sv[rt2 * 4 + jj];
        float z1 = fmaf(sp.x, w10, fmaf(sp.y, w11, bb));
        float sg = __builtin_amdgcn_rcpf(1.f + __expf(-z1));
        float dz1 = acc2[rt2][ct2][jj] * sg;
        p0[rt2 * 4 + jj] = fmaf(dz1, w10, p0[rt2 * 4 + jj]);
        p1v[rt2 * 4 + jj] = fmaf(dz1, w11, p1v[rt2 * 4 + jj]);
      }
    }
  }

  // reduce partials across the 16 lanes of each row-group
#pragma unroll
  for (int i = 0; i < 16; ++i) {
    float a = p0[i], b = p1v[i];
    for (int m = 1; m < 16; m <<= 1) {
      a += __shfl_xor(a, m, 64);
      b += __shfl_xor(b, m, 64);
    }
    p0[i] = a;
    p1v[i] = b;
  }
  if (l15 == 0) {
#pragma unroll
    for (int rt2 = 0; rt2 < 4; ++rt2)
#pragma unroll
      for (int jj = 0; jj < 4; ++jj) {
        int r = rt2 * 16 + l4 * 4 + jj;
        part[wid][r][0] = p0[rt2 * 4 + jj];
        part[wid][r][1] = p1v[rt2 * 4 + jj];
      }
  }
  __syncthreads();

  // ---- final: combine waves, damping + action term, write (B,2) ----
  if (t < 64) {
    long grow = row0 + t;
    float g0 = part[0][t][0] + part[1][t][0] + part[2][t][0] + part[3][t][0];
    float g1 = part[0][t][1] + part[1][t][1] + part[2][t][1] + part[3][t][1];
    const float4 ae0 = reinterpret_cast<const float4*>(action_emb)[grow * 2];
    const float4 ae1 = reinterpret_cast<const float4*>(action_emb)[grow * 2 + 1];
    float gu = Gb[0];
    gu = fmaf(ae0.x, Gw[0], gu);
    gu = fmaf(ae0.y, Gw[1], gu);
    gu = fmaf(ae0.z, Gw[2], gu);
    gu = fmaf(ae0.w, Gw[3], gu);
    gu = fmaf(ae1.x, Gw[4], gu);
    gu = fmaf(ae1.y, Gw[5], gu);
    gu = fmaf(ae1.z, Gw[6], gu);
    gu = fmaf(ae1.w, Gw[7], gu);
    float damping = __expf(log_damping[0]);
    float2 o;
    o.x = g1;                              // dq_dt = dH_dp
    o.y = -g0 - damping * g1 + gu;         // dp_dt
    reinterpret_cast<float2*>(out)[grow] = o;
  }
}

extern "C" void kernel_launch(void* const* d_in, const int* in_sizes, int n_in,
                              void* d_out, int out_size, void* d_ws,
                              size_t ws_size, hipStream_t stream) {
  // setup_inputs order: t, state, action_emb, W1, b1, W2, b2, W3, b3,
  //                     log_damping, Gw, Gb
  const float* state = (const float*)d_in[1];
  const float* action_emb = (const float*)d_in[2];
  const float* W1 = (const float*)d_in[3];
  const float* b1 = (const float*)d_in[4];
  const float* W2 = (const float*)d_in[5];
  const float* b2 = (const float*)d_in[6];
  const float* W3 = (const float*)d_in[7];
  const float* log_damping = (const float*)d_in[9];
  const float* Gw = (const float*)d_in[10];
  const float* Gb = (const float*)d_in[11];
  float* out = (float*)d_out;

  unsigned short* p1 = (unsigned short*)d_ws;       // 512KB packed W2 (32x32 frags)
  unsigned short* p2 = p1 + 262144;                 // 512KB packed W2^T (16x16 frags)

  pack_w2_kernel<<<dim3(2048), dim3(256), 0, stream>>>(W2, p1, p2);
  phm_kernel<<<dim3(2048), dim3(256), 0, stream>>>(
      state, action_emb, W1, b1, b2, W3, log_damping, Gw, Gb, p1, p2, out);
}

// Round 4
// 155.217 us; speedup vs baseline: 1.1442x; 1.1442x over previous
//
#include <hip/hip_runtime.h>

typedef __bf16 bf16x8 __attribute__((ext_vector_type(8)));
typedef float f32x4 __attribute__((ext_vector_type(4)));
typedef float f32x16 __attribute__((ext_vector_type(16)));
typedef unsigned short u16x8 __attribute__((ext_vector_type(8)));

#define DEVI static __device__ __forceinline__

DEVI unsigned short f2b(float x) {
  __bf16 b = (__bf16)x;           // native v_cvt, RNE
  return __builtin_bit_cast(unsigned short, b);
}

DEVI float ex2(float x) {         // exp2
#if __has_builtin(__builtin_amdgcn_exp2f)
  return __builtin_amdgcn_exp2f(x);
#else
  return __expf(x * 0.69314718f);
#endif
}
DEVI float lg2(float x) {         // log2
#if __has_builtin(__builtin_amdgcn_logf)
  return __builtin_amdgcn_logf(x);
#else
  return __logf(x) * 1.44269504f;
#endif
}

// Pre-pack W2 into per-lane MFMA B-fragment order, bf16 (unchanged, verified).
__global__ __launch_bounds__(256) void pack_w2_kernel(
    const float* __restrict__ W2, unsigned short* __restrict__ p1,
    unsigned short* __restrict__ p2) {
  int idx = blockIdx.x * 256 + threadIdx.x;   // 0 .. 524287
  int which = idx >> 18;
  int i = idx & 262143;
  int j = i & 7;
  int l = (i >> 3) & 63;
  if (which == 0) {
    int t0 = (i >> 9) & 15;
    int s = i >> 13;            // 0..31
    p1[i] = f2b(W2[(s * 16 + (l >> 5) * 8 + j) * 512 + t0 * 32 + (l & 31)]);
  } else {
    int t0 = (i >> 9) & 31;
    int s = i >> 14;            // 0..15
    p2[i] = f2b(W2[(t0 * 16 + (l & 15)) * 512 + s * 32 + (l >> 4) * 8 + j]);
  }
}

__global__ __launch_bounds__(512, 4) void phm_kernel(
    const float* __restrict__ state, const float* __restrict__ action_emb,
    const float* __restrict__ W1, const float* __restrict__ b1,
    const float* __restrict__ b2, const float* __restrict__ W3,
    const float* __restrict__ log_damping, const float* __restrict__ Gw,
    const float* __restrict__ Gb, const unsigned short* __restrict__ packB1,
    const unsigned short* __restrict__ packB2, float* __restrict__ out) {
  // buf reused: GEMM1 A-fragments (h1*log2e) -> GEMM2 A-fragments (dz2).
  __shared__ unsigned short buf[64 * 512];   // 64KB
  __shared__ float W1s[1024];                // W1 * log2e
  __shared__ float b1s[512];                 // b1 * log2e
  __shared__ float b2s[512];                 // b2 * log2e
  __shared__ float W3s[512];
  __shared__ float st[128];
  __shared__ float2 part2[8][64];

  const int t = threadIdx.x;
  const int lane = t & 63;
  const int wid = t >> 6;       // 0..7
  const int l15 = lane & 15;
  const int l4 = lane >> 4;
  const int l31 = lane & 31;
  const int l5 = lane >> 5;
  const long row0 = (long)blockIdx.x * 64;
  char* bufc = reinterpret_cast<char*>(buf);
  const float LOG2E = 1.44269504f;

  // ---- stage small tables (log2e-folded) ----
  for (int i = t; i < 512; i += 512) {
    W1s[i] = W1[i] * LOG2E;
    W1s[512 + i] = W1[512 + i] * LOG2E;
    b1s[i] = b1[i] * LOG2E;
    b2s[i] = b2[i] * LOG2E;
    W3s[i] = W3[i];
  }
  if (t < 128) st[t] = state[row0 * 2 + t];
  __syncthreads();

  // ---- phase 0: h' = log2e*softplus(z1) -> GEMM1-A fragments ----
  // page = s*2+rt: lane holds h'[row = rt*32+(l&31)][k = s*16+(l>>5)*8+j]
#pragma unroll
  for (int it = 0; it < 8; ++it) {
    int page = it * 8 + wid;
    int s = page >> 1, rt = page & 1;
    int row = rt * 32 + l31;
    int k0 = s * 16 + l5 * 8;
    float s0 = st[row * 2], s1 = st[row * 2 + 1];
    u16x8 pk;
#pragma unroll
    for (int j = 0; j < 8; ++j) {
      int c = k0 + j;
      float zp = fmaf(s0, W1s[c], fmaf(s1, W1s[512 + c], b1s[c]));  // z1*log2e
      float hp = fmaxf(zp, 0.f) + lg2(1.f + ex2(-fabsf(zp)));       // h1*log2e
      pk[j] = f2b(hp);
    }
    *reinterpret_cast<u16x8*>(bufc + page * 1024 + lane * 16) = pk;
  }
  __syncthreads();

  // ---- GEMM1: acc = h' @ W2 = z2*log2e ; each wave owns 64 cols ----
  f32x16 acc1[2][2];
#pragma unroll
  for (int rt = 0; rt < 2; ++rt)
#pragma unroll
    for (int ct = 0; ct < 2; ++ct)
#pragma unroll
      for (int r = 0; r < 16; ++r) acc1[rt][ct][r] = 0.f;

#pragma unroll 2
  for (int s = 0; s < 32; ++s) {
    bf16x8 af[2];
#pragma unroll
    for (int rt = 0; rt < 2; ++rt)
      af[rt] = __builtin_bit_cast(
          bf16x8, *reinterpret_cast<const int4*>(
                      bufc + (s * 2 + rt) * 1024 + lane * 16));
    bf16x8 bfr[2];
#pragma unroll
    for (int ct = 0; ct < 2; ++ct)
      bfr[ct] = __builtin_bit_cast(
          bf16x8, *reinterpret_cast<const int4*>(
                      packB1 + ((s * 16 + wid * 2 + ct) * 64 + lane) * 8));
#pragma unroll
    for (int rt = 0; rt < 2; ++rt)
#pragma unroll
      for (int ct = 0; ct < 2; ++ct)
        acc1[rt][ct] = __builtin_amdgcn_mfma_f32_32x32x16_bf16(
            af[rt], bfr[ct], acc1[rt][ct], 0, 0, 0);
  }
  __syncthreads();   // all waves done reading h' fragments

  // ---- epi1: dz2 = W3 * sigmoid(z2+b2) -> GEMM2-A fragments (xor slots) ----
#pragma unroll
  for (int ct = 0; ct < 2; ++ct) {
    int c = (wid * 2 + ct) * 32 + l31;
    float w3 = W3s[c], bbL = b2s[c];
    int pbase = (c >> 5) * 4096 + (c & 7) * 2;
    int oct = (c >> 3) & 3;
#pragma unroll
    for (int rt = 0; rt < 2; ++rt) {
#pragma unroll
      for (int reg = 0; reg < 16; ++reg) {
        int row = rt * 32 + (reg & 3) + 8 * (reg >> 2) + 4 * l5;
        float e = ex2(-(acc1[rt][ct][reg] + bbL));   // exp(-(z2+b2))
        float sg = __builtin_amdgcn_rcpf(1.f + e);
        unsigned short u = f2b(w3 * sg);
        int lane2 = (row & 15) + 16 * oct;
        int slot = lane2 ^ (lane2 >> 4);
        *reinterpret_cast<unsigned short*>(
            bufc + pbase + (row >> 4) * 1024 + slot * 16) = u;
      }
    }
  }
  __syncthreads();

  // ---- GEMM2 (chunked) + epi2: dh1 = dz2 @ W2^T; dz1 = dh1*sig(z1) ----
  float p0[16], p1v[16];
#pragma unroll
  for (int i = 0; i < 16; ++i) { p0[i] = 0.f; p1v[i] = 0.f; }

  const int rslot = (lane ^ (lane >> 4)) * 16;
#pragma unroll
  for (int chunk = 0; chunk < 2; ++chunk) {
    f32x4 acc2[4][2];
#pragma unroll
    for (int a = 0; a < 4; ++a)
#pragma unroll
      for (int b = 0; b < 2; ++b)
#pragma unroll
        for (int r = 0; r < 4; ++r) acc2[a][b][r] = 0.f;

#pragma unroll 2
    for (int s2 = 0; s2 < 16; ++s2) {
      bf16x8 af[4];
#pragma unroll
      for (int rt2 = 0; rt2 < 4; ++rt2)
        af[rt2] = __builtin_bit_cast(
            bf16x8, *reinterpret_cast<const int4*>(
                        bufc + s2 * 4096 + rt2 * 1024 + rslot));
      bf16x8 bfr[2];
#pragma unroll
      for (int cc = 0; cc < 2; ++cc)
        bfr[cc] = __builtin_bit_cast(
            bf16x8,
            *reinterpret_cast<const int4*>(
                packB2 + ((s2 * 32 + wid * 4 + chunk * 2 + cc) * 64 + lane) * 8));
#pragma unroll
      for (int rt2 = 0; rt2 < 4; ++rt2)
#pragma unroll
        for (int cc = 0; cc < 2; ++cc)
          acc2[rt2][cc] = __builtin_amdgcn_mfma_f32_16x16x32_bf16(
              af[rt2], bfr[cc], acc2[rt2][cc], 0, 0, 0);
    }
    // epilogue for this chunk (C/D: col=l&15, row=(l>>4)*4+j)
#pragma unroll
    for (int rt2 = 0; rt2 < 4; ++rt2) {
      float2 rv[4];
#pragma unroll
      for (int jj = 0; jj < 4; ++jj)
        rv[jj] = *reinterpret_cast<const float2*>(
            &st[(rt2 * 16 + l4 * 4 + jj) * 2]);
#pragma unroll
      for (int cc = 0; cc < 2; ++cc) {
        int hc = wid * 64 + (chunk * 2 + cc) * 16 + l15;
        float w10L = W1s[hc], w11L = W1s[512 + hc], bbL = b1s[hc];
#pragma unroll
        for (int jj = 0; jj < 4; ++jj) {
          float z1L = fmaf(rv[jj].x, w10L, fmaf(rv[jj].y, w11L, bbL));
          float sg = __builtin_amdgcn_rcpf(1.f + ex2(-z1L));
          float dz1 = acc2[rt2][cc][jj] * sg;
          p0[rt2 * 4 + jj] = fmaf(dz1, w10L, p0[rt2 * 4 + jj]);
          p1v[rt2 * 4 + jj] = fmaf(dz1, w11L, p1v[rt2 * 4 + jj]);
        }
      }
    }
  }

  // ---- folding reduce across 16 lanes: lane ends owning row i = l15 ----
  float a8[8], b8[8];
  {
    bool bb = (l15 & 1) != 0;
#pragma unroll
    for (int m = 0; m < 8; ++m) {
      float ka = bb ? p0[2 * m + 1] : p0[2 * m];
      float sa = bb ? p0[2 * m] : p0[2 * m + 1];
      a8[m] = ka + __shfl_xor(sa, 1, 64);
      float kb = bb ? p1v[2 * m + 1] : p1v[2 * m];
      float sb = bb ? p1v[2 * m] : p1v[2 * m + 1];
      b8[m] = kb + __shfl_xor(sb, 1, 64);
    }
  }
  float a4[4], b4[4];
  {
    bool bb = (l15 & 2) != 0;
#pragma unroll
    for (int m = 0; m < 4; ++m) {
      float ka = bb ? a8[2 * m + 1] : a8[2 * m];
      float sa = bb ? a8[2 * m] : a8[2 * m + 1];
      a4[m] = ka + __shfl_xor(sa, 2, 64);
      float kb = bb ? b8[2 * m + 1] : b8[2 * m];
      float sb = bb ? b8[2 * m] : b8[2 * m + 1];
      b4[m] = kb + __shfl_xor(sb, 2, 64);
    }
  }
  float a2[2], b2v[2];
  {
    bool bb = (l15 & 4) != 0;
#pragma unroll
    for (int m = 0; m < 2; ++m) {
      float ka = bb ? a4[2 * m + 1] : a4[2 * m];
      float sa = bb ? a4[2 * m] : a4[2 * m + 1];
      a2[m] = ka + __shfl_xor(sa, 4, 64);
      float kb = bb ? b4[2 * m + 1] : b4[2 * m];
      float sb = bb ? b4[2 * m] : b4[2 * m + 1];
      b2v[m] = kb + __shfl_xor(sb, 4, 64);
    }
  }
  float a1, b1r;
  {
    bool bb = (l15 & 8) != 0;
    float ka = bb ? a2[1] : a2[0];
    float sa = bb ? a2[0] : a2[1];
    a1 = ka + __shfl_xor(sa, 8, 64);
    float kb = bb ? b2v[1] : b2v[0];
    float sb = bb ? b2v[0] : b2v[1];
    b1r = kb + __shfl_xor(sb, 8, 64);
  }
  {
    int r = (l15 >> 2) * 16 + l4 * 4 + (l15 & 3);
    part2[wid][r] = make_float2(a1, b1r);
  }
  __syncthreads();

  // ---- final: combine waves, ln2 fix-up, damping + action term ----
  if (t < 64) {
    long grow = row0 + t;
    float g0 = 0.f, g1 = 0.f;
#pragma unroll
    for (int w = 0; w < 8; ++w) {
      float2 pp = part2[w][t];
      g0 += pp.x;
      g1 += pp.y;
    }
    const float LN2 = 0.69314718f;
    g0 *= LN2;                 // partials were accumulated with log2e-scaled W1
    g1 *= LN2;
    const float4 ae0 = reinterpret_cast<const float4*>(action_emb)[grow * 2];
    const float4 ae1 = reinterpret_cast<const float4*>(action_emb)[grow * 2 + 1];
    float gu = Gb[0];
    gu = fmaf(ae0.x, Gw[0], gu);
    gu = fmaf(ae0.y, Gw[1], gu);
    gu = fmaf(ae0.z, Gw[2], gu);
    gu = fmaf(ae0.w, Gw[3], gu);
    gu = fmaf(ae1.x, Gw[4], gu);
    gu = fmaf(ae1.y, Gw[5], gu);
    gu = fmaf(ae1.z, Gw[6], gu);
    gu = fmaf(ae1.w, Gw[7], gu);
    float damping = __expf(log_damping[0]);
    float2 o;
    o.x = g1;                              // dq_dt = dH_dp
    o.y = -g0 - damping * g1 + gu;         // dp_dt
    reinterpret_cast<float2*>(out)[grow] = o;
  }
}

extern "C" void kernel_launch(void* const* d_in, const int* in_sizes, int n_in,
                              void* d_out, int out_size, void* d_ws,
                              size_t ws_size, hipStream_t stream) {
  // setup_inputs order: t, state, action_emb, W1, b1, W2, b2, W3, b3,
  //                     log_damping, Gw, Gb
  const float* state = (const float*)d_in[1];
  const float* action_emb = (const float*)d_in[2];
  const float* W1 = (const float*)d_in[3];
  const float* b1 = (const float*)d_in[4];
  const float* W2 = (const float*)d_in[5];
  const float* b2 = (const float*)d_in[6];
  const float* W3 = (const float*)d_in[7];
  const float* log_damping = (const float*)d_in[9];
  const float* Gw = (const float*)d_in[10];
  const float* Gb = (const float*)d_in[11];
  float* out = (float*)d_out;

  unsigned short* p1 = (unsigned short*)d_ws;       // 512KB packed W2 (32x32 frags)
  unsigned short* p2 = p1 + 262144;                 // 512KB packed W2^T (16x16 frags)

  pack_w2_kernel<<<dim3(2048), dim3(256), 0, stream>>>(W2, p1, p2);
  phm_kernel<<<dim3(2048), dim3(512), 0, stream>>>(
      state, action_emb, W1, b1, b2, W3, log_damping, Gw, Gb, p1, p2, out);
}